// Round 1
// baseline (59.304 us; speedup 1.0000x reference)
//
#include <hip/hip_runtime.h>

// Sliding-window variance, window W=64 looking forward, clipped at row end.
// x: (B=32, L=16384) fp32 row-major; out: (B, L) fp32.
// var[b,i] = Var(x[b, i : min(i+W, L)])   (population variance, divide by n)

constexpr int W      = 64;
constexpr int K      = 4;                 // outputs per thread
constexpr int T      = 256;               // threads per block
constexpr int CHUNK  = T * K;             // 1024 outputs per block
constexpr int LDS_F4 = (CHUNK + W) / 4;   // 272 float4 = 1088 floats (need 1087)

__global__ __launch_bounds__(T) void sliding_var64_kernel(
    const float* __restrict__ x, float* __restrict__ out,
    int L, int chunksPerRow)
{
    __shared__ float4 lds4[LDS_F4];
    float* lds = reinterpret_cast<float*>(lds4);

    const int row = blockIdx.x / chunksPerRow;
    const int c0  = (blockIdx.x % chunksPerRow) * CHUNK;
    const float* xr   = x   + (size_t)row * L;
    float*       outr = out + (size_t)row * L;
    const int tid = threadIdx.x;

    // ---- stage CHUNK + W floats into LDS, coalesced float4 loads ----
    // (xr + c0) is 16B-aligned: c0 is a multiple of 1024, rows are multiples of L.
    const float4* src4 = reinterpret_cast<const float4*>(xr + c0);
    for (int i = tid; i < LDS_F4; i += T) {
        const int g4 = c0 + 4 * i;          // global float index of this float4
        float4 v;
        if (g4 + 3 < L) {
            v = src4[i];
        } else {                             // row-end halo: clamp with zeros
            v.x = (g4 + 0 < L) ? xr[g4 + 0] : 0.0f;
            v.y = (g4 + 1 < L) ? xr[g4 + 1] : 0.0f;
            v.z = (g4 + 2 < L) ? xr[g4 + 2] : 0.0f;
            v.w = (g4 + 3 < L) ? xr[g4 + 3] : 0.0f;
        }
        lds4[i] = v;
    }
    __syncthreads();

    // ---- pull this thread's 68-float window span into registers ----
    // thread t covers outputs [4t, 4t+3]; needs elements [4t, 4t+67].
    // lds4[tid + jj]: consecutive lanes -> consecutive float4s, conflict-free.
    float wr[68];
    #pragma unroll
    for (int jj = 0; jj < 17; ++jj) {
        const float4 v = lds4[tid + jj];
        wr[4 * jj + 0] = v.x;
        wr[4 * jj + 1] = v.y;
        wr[4 * jj + 2] = v.z;
        wr[4 * jj + 3] = v.w;
    }

    // first window's sum / sum-of-squares (all indices compile-time constant)
    float s = 0.0f, q = 0.0f;
    #pragma unroll
    for (int j = 0; j < W; ++j) {
        s += wr[j];
        q = fmaf(wr[j], wr[j], q);
    }

    const int base = tid * K;                // local output index of k=0
    float4 res;
    float* resf = reinterpret_cast<float*>(&res);

    #pragma unroll
    for (int k = 0; k < K; ++k) {
        const int g = c0 + base + k;         // global output index (< L always)
        const int n = L - g;                 // valid elements in window
        float var;
        if (n >= W) {
            const float mean = s * (1.0f / W);
            var = fmaxf(fmaf(-mean, mean, q * (1.0f / W)), 0.0f);
        } else {
            // rare tail path (last 63 positions of a row): recompute from LDS
            float ss = 0.0f, qq = 0.0f;
            for (int j = 0; j < n; ++j) {
                const float v = lds[base + k + j];
                ss += v;
                qq = fmaf(v, v, qq);
            }
            const float mean = ss / n;
            var = fmaxf(fmaf(-mean, mean, qq / n), 0.0f);
        }
        resf[k] = var;
        if (k < K - 1) {                     // slide window by one
            const float a = wr[k + W], b = wr[k];
            s += a - b;
            q += fmaf(a, a, -(b * b));
        }
    }

    // float4 store: outputs [c0+4t .. c0+4t+3], 16B-aligned
    *reinterpret_cast<float4*>(outr + c0 + base) = res;
}

extern "C" void kernel_launch(void* const* d_in, const int* in_sizes, int n_in,
                              void* d_out, int out_size, void* d_ws, size_t ws_size,
                              hipStream_t stream)
{
    const float* x = (const float*)d_in[0];
    float* out = (float*)d_out;

    const int L = 16384;                  // from setup_inputs
    const int B = out_size / L;           // 32
    const int chunksPerRow = L / CHUNK;   // 16 (L divisible by CHUNK)

    dim3 grid(B * chunksPerRow), block(T);
    hipLaunchKernelGGL(sliding_var64_kernel, grid, block, 0, stream,
                       x, out, L, chunksPerRow);
}